// Round 19
// baseline (56.489 us; speedup 1.0000x reference)
//
#include <hip/hip_runtime.h>
#include <hip/hip_bf16.h>
#include <math.h>

#define MRAY 16
#define BLOCK 256
#define GRID 1024   // persistent: 1024 blocks x 4 groups x 16 pts = 65536
#define GPB 4       // groups per block

typedef float f2 __attribute__((ext_vector_type(2)));
typedef float f4 __attribute__((ext_vector_type(4)));
typedef _Float16 h8 __attribute__((ext_vector_type(8)));
typedef _Float16 h4 __attribute__((ext_vector_type(4)));
typedef __fp16 fp16x2 __attribute__((ext_vector_type(2)));

__device__ __forceinline__ float sigmoidf_(float x){ return 1.0f/(1.0f+__expf(-x)); }
__device__ __forceinline__ f2 shflxor2(f2 v, int off){
    f2 r; r.x = __shfl_xor(v.x, off); r.y = __shfl_xor(v.y, off); return r;
}
__device__ __forceinline__ f4 mfma16(h8 a, h8 b, f4 c){
    return __builtin_amdgcn_mfma_f32_16x16x32_f16(a, b, c, 0, 0, 0);
}
__device__ __forceinline__ f4 mfma16k16(h4 a, h4 b, f4 c){
    return __builtin_amdgcn_mfma_f32_16x16x16f16(a, b, c, 0, 0, 0);
}
__device__ __forceinline__ int pkh(float a, float b){
    union { fp16x2 h; int i; } u;
    u.h = __builtin_amdgcn_cvt_pkrtz(a, b);
    return u.i;
}
// packed f16 relu on a 2xf16 word
__device__ __forceinline__ int relu2h(int w){
    union { int i; fp16x2 h; } u; u.i = w;
    fp16x2 z = {(__fp16)0.f, (__fp16)0.f};
    u.h = __builtin_elementwise_max(u.h, z);
    return u.i;
}

// ws float layout:
//   [0]      flag (int)
//   [16]     fragDT:  h8[1024]  (TRANSPOSED Wd1: A[row=j][k], k-order [app48,xyz3,vdir3,pad10], 2 Ksteps)
//   [4112]   fragB:   h8[1024]  (Wb1 const rows, k-order [nf48,eV3,eN3,pad10])
//   [8208]   fragRT:  h8[512]   (transposed ray weights: A[row=j][k], k<9 -> Wb1 ray rows, k==9 -> row63)
//   [10256]  fragW2:  h4[512]   (A-frag layer-2 ray: rows 4q+c = Wb2^T[c] (c<3), row 4q+3 = 0)
//   [11280]  fragWd2t:h4[512]   (A-frag layer-2 dense: rows 4q+c = Wd2^T[{0,1,2,6}[c]])
__global__ __launch_bounds__(256) void prep(
    const float* __restrict__ Wd1, const float* __restrict__ Wb1,
    const float* __restrict__ Wb2, const float* __restrict__ Wd2,
    const unsigned int* __restrict__ rm, float* __restrict__ ws)
{
    const int gt = blockIdx.x*256 + threadIdx.x;
    h8* fragDT  = (h8*)(ws + 16);
    h8* fragB   = fragDT + 1024;
    h8* fragRT  = fragB + 1024;
    h4* fragW2  = (h4*)(ws + 10256);
    h4* fragWd2t= (h4*)(ws + 11280);
    if (gt < 1024){
        int ks = gt >> 9, t = (gt >> 6) & 7, l = gt & 63;
        int j = 16*t + (l & 15), gg = (l >> 4) & 3;
        h8 v;
        #pragma unroll
        for (int b = 0; b < 8; b++){
            int k = 32*ks + 8*gg + b;
            int row = (k < 48) ? 6 + k : (k < 54 ? k - 48 : -1);
            v[b] = (_Float16)(row >= 0 ? Wd1[row*128 + j] : 0.0f);
        }
        fragDT[gt] = v;
    } else if (gt < 2048){
        int e = gt - 1024;
        int ks = e >> 9, t = (e >> 6) & 7, l = e & 63;
        int col = 16*t + (l & 15), gg = (l >> 4) & 3;
        h8 v;
        #pragma unroll
        for (int b = 0; b < 8; b++){
            int k = 32*ks + 8*gg + b;
            int row = (k < 48) ? 15 + k : (k < 51 ? k - 48 : (k < 54 ? k - 45 : -1));
            v[b] = (_Float16)(row >= 0 ? Wb1[row*128 + col] : 0.0f);
        }
        fragB[e] = v;
    } else if (gt < 2560){
        int e = gt - 2048;
        int t = e >> 6, l = e & 63;
        int j = 16*t + (l & 15), gg = (l >> 4) & 3;
        h8 v;
        #pragma unroll
        for (int b = 0; b < 8; b++){
            int k = 8*gg + b;
            int row = (k < 3) ? 3 + k : (k < 9 ? 6 + k : (k == 9 ? 63 : -1));
            v[b] = (_Float16)(row >= 0 ? Wb1[row*128 + j] : 0.0f);
        }
        fragRT[e] = v;
    } else if (gt < 3072){
        int e = gt - 2560;
        int t = e >> 6, l = e & 63;
        int r = l & 15, kg = (l >> 4) & 3;
        int c = r & 3;
        h4 v;
        #pragma unroll
        for (int i = 0; i < 4; i++){
            int j = 16*t + 4*kg + i;
            v[i] = (_Float16)((c < 3) ? Wb2[j*3 + c] : 0.0f);
        }
        fragW2[e] = v;
    } else if (gt < 3584){
        int e = gt - 3072;
        int t = e >> 6, l = e & 63;
        int r = l & 15, kg = (l >> 4) & 3;
        int c = r & 3;
        int col = (c == 3) ? 6 : c;
        h4 v;
        #pragma unroll
        for (int i = 0; i < 4; i++){
            int j = 16*t + 4*kg + i;
            v[i] = (_Float16)Wd2[j*9 + col];
        }
        fragWd2t[e] = v;
    } else if (gt >= 3584 && gt < 3648){
        int l = gt - 3584;
        bool bad=false, isf32=false, odd_nz=false, even_one=false;
        #pragma unroll
        for (int i = 0; i < 8; i++){
            int idx = l*8 + i;
            unsigned v = rm[idx];
            if (v != 0u && v != 1u && v != 0x3F800000u) bad = true;
            if (v == 0x3F800000u) isf32 = true;
            if ((idx & 1) && v != 0u) odd_nz = true;
            if (!(idx & 1) && v != 0u) even_one = true;
        }
        unsigned long long Bb = __ballot(bad);
        unsigned long long Bf = __ballot(isf32);
        unsigned long long Bo = __ballot(odd_nz);
        unsigned long long Be = __ballot(even_one);
        if (l == 0){
            int f;
            if (Bb) f = 0;
            else if (Bf) f = 1;
            else if (!Bo && Be) f = 2;
            else f = 1;
            ((int*)ws)[0] = f;
        }
    }
}

// Persistent blocks: each block processes GPB groups of 16 points. Per group:
// cooperative pre-phase (wave w: N-tiles {2w,2w+1}) with both layer-2s fused
// via chained MFMA; one barrier; ray phase (chunk ch=wid); loop-end barrier.
__global__ __launch_bounds__(BLOCK, 2) void rb_main(
    const float* __restrict__ xyzs, const float* __restrict__ app,
    const float* __restrict__ vdirs, const float* __restrict__ normals,
    const float* __restrict__ noise, const float* __restrict__ uu,
    const float* __restrict__ bd1, const float* __restrict__ bd2,
    const float* __restrict__ bb1, const float* __restrict__ bb2,
    const void* __restrict__ raym, const float* __restrict__ wsf,
    float* __restrict__ out)
{
    __shared__ float baseL[16*132];
    __shared__ float psum[4][16][4];

    const int tid  = threadIdx.x;
    const int lane = tid & 63;
    const int ch   = __builtin_amdgcn_readfirstlane(tid >> 6);

    const int flag = ((const int*)wsf)[0];
    const h8* fragDT  = (const h8*)(wsf + 16);
    const h8* fragB   = fragDT + 1024;
    const h8* fragRT  = fragB + 1024;
    const h4* fragW2  = (const h4*)(wsf + 10256);
    const h4* fragWd2t= (const h4*)(wsf + 11280);

    const int c15 = lane & 15;
    const int kg  = lane >> 4;

    for (int grp = 0; grp < GPB; grp++){
        const int pbase = (blockIdx.x * GPB + grp) * 16;
        const int myp = 4*ch + kg;
        const int myn = pbase + myp;

        // ---- prefetch: uu pair + ray-mask decode (lane-local: pt=myp, ray=c15) ----
        f2 uv = *(const f2*)&uu[(myn*MRAY + c15)*2];
        float mf0;
        {
            int midx = myn*MRAY + c15;
            bool mk;
            if (flag == 0)      mk = ((const unsigned char*)raym)[midx] != 0;
            else if (flag == 2) mk = ((const unsigned long long*)raym)[midx] != 0ull;
            else                mk = ((const unsigned int*)raym)[midx] != 0u;
            mf0 = mk ? 1.f : 0.f;
        }

        // ---- in-lane basis + local V for OWN point myn ----
        float bas[9], Vlx, Vly, Vlz;
        {
            float nx = normals[myn*3+0], ny = normals[myn*3+1], nz2 = normals[myn*3+2];
            float inv = 1.0f/(sqrtf(nx*nx+ny*ny+nz2*nz2)+1e-8f);
            float bx = nx*inv, by = ny*inv, bz = nz2*inv;
            float ux, uy, uz;
            if (fabsf(bz) < 0.99f){ ux=0.f; uy=0.f; uz=1.f; } else { ux=1.f; uy=0.f; uz=0.f; }
            float tx = uy*bz-uz*by, ty = uz*bx-ux*bz, tz = ux*by-uy*bx;
            float tin = 1.0f/(sqrtf(tx*tx+ty*ty+tz*tz)+1e-8f);
            tx*=tin; ty*=tin; tz*=tin;
            float ex = by*tz-bz*ty, ey = bz*tx-bx*tz, ez = bx*ty-by*tx;
            bas[0]=tx; bas[1]=ex; bas[2]=bx;
            bas[3]=ty; bas[4]=ey; bas[5]=by;
            bas[6]=tz; bas[7]=ez; bas[8]=bz;
            float vx = vdirs[myn*3+0], vy = vdirs[myn*3+1], vz = vdirs[myn*3+2];
            Vlx = -(tx*vx + ty*vy + tz*vz);
            Vly = -(ex*vx + ey*vy + ez*vz);
            Vlz = -(bx*vx + by*vy + bz*vz);
        }

        // ---- input fragments for GEMM1/2 (lane: pt = c15, k-slice = kg) ----
        const int n_p = pbase + c15;
        float xv0=0.f,xv1=0.f,xv2=0.f,vv0=0.f,vv1=0.f,vv2=0.f;
        if (kg == 2){
            xv0 = xyzs[n_p*3+0]; xv1 = xyzs[n_p*3+1]; xv2 = xyzs[n_p*3+2];
            vv0 = vdirs[n_p*3+0]; vv1 = vdirs[n_p*3+1]; vv2 = vdirs[n_p*3+2];
        }
        float bn0, bn1, bn2;
        {
            float nx = normals[n_p*3+0], ny = normals[n_p*3+1], nz2 = normals[n_p*3+2];
            float inv = 1.0f/(sqrtf(nx*nx+ny*ny+nz2*nz2)+1e-8f);
            bn0 = nx*inv; bn1 = ny*inv; bn2 = nz2*inv;
        }
        const float* ap = app + n_p*48;
        const float* nz = noise + n_p*48;
        h8 afD[2], afB[2];
        #pragma unroll
        for (int ks = 0; ks < 2; ks++){
            const int k0 = 32*ks + 8*kg;
            union { int i[4]; h8 h; } UD, UB;
            if (k0 <= 40){
                f4 a0 = *(const f4*)(ap + k0);
                f4 a1 = *(const f4*)(ap + k0 + 4);
                f4 z0 = *(const f4*)(nz + k0);
                f4 z1 = *(const f4*)(nz + k0 + 4);
                UD.i[0] = pkh(a0.x, a0.y); UD.i[1] = pkh(a0.z, a0.w);
                UD.i[2] = pkh(a1.x, a1.y); UD.i[3] = pkh(a1.z, a1.w);
                UB.i[0] = pkh(fmaf(0.01f,z0.x,a0.x), fmaf(0.01f,z0.y,a0.y));
                UB.i[1] = pkh(fmaf(0.01f,z0.z,a0.z), fmaf(0.01f,z0.w,a0.w));
                UB.i[2] = pkh(fmaf(0.01f,z1.x,a1.x), fmaf(0.01f,z1.y,a1.y));
                UB.i[3] = pkh(fmaf(0.01f,z1.z,a1.z), fmaf(0.01f,z1.w,a1.w));
            } else if (k0 == 48){
                UD.i[0] = pkh(xv0, xv1); UD.i[1] = pkh(xv2, vv0);
                UD.i[2] = pkh(vv1, vv2); UD.i[3] = 0;
                UB.i[0] = pkh(-vv0, -vv1); UB.i[1] = pkh(-vv2, bn0);
                UB.i[2] = pkh(bn1, bn2);   UB.i[3] = 0;
            } else {
                UD.i[0]=0; UD.i[1]=0; UD.i[2]=0; UD.i[3]=0;
                UB.i[0]=0; UB.i[1]=0; UB.i[2]=0; UB.i[3]=0;
            }
            afD[ks]=UD.h; afB[ks]=UB.h;
        }

        // ---- GEMM1 transposed chained into layer-2 MFMA, 2 N-tiles ----
        f4 S1 = {0.f,0.f,0.f,0.f};
        #pragma unroll
        for (int tt = 0; tt < 2; tt++){
            const int t = 2*ch + tt;
            const int j0 = 16*t + 4*kg;
            f4 C = *(const f4*)&bd1[j0];
            f4 d = mfma16(fragDT[t*64 + lane], afD[0], C);
            d = mfma16(fragDT[512 + t*64 + lane], afD[1], d);
            union { int i[2]; h4 h; } B2;
            B2.i[0] = relu2h(pkh(d.x, d.y));
            B2.i[1] = relu2h(pkh(d.z, d.w));
            S1 = mfma16k16(fragWd2t[t*64 + lane], B2.h, S1);
        }
        if (kg == 0)
            *(f4*)&psum[ch][c15][0] = S1;

        // ---- GEMM2 (bounce const part), 2 N-tiles -> baseL ----
        #pragma unroll
        for (int tt = 0; tt < 2; tt++){
            const int t = 2*ch + tt;
            const int col = 16*t + c15;
            float bias = bb1[col];
            f4 D = {bias,bias,bias,bias};
            D = mfma16(afB[0], fragB[t*64 + lane], D);
            D = mfma16(afB[1], fragB[512 + t*64 + lane], D);
            baseL[(4*kg+0)*132 + col] = D.x;
            baseL[(4*kg+1)*132 + col] = D.y;
            baseL[(4*kg+2)*132 + col] = D.z;
            baseL[(4*kg+3)*132 + col] = D.w;
        }

        __syncthreads();   // psum + baseL complete

        // ---- scalars for THIS lane's point (LDS broadcast reads) ----
        f4 sv = *(const f4*)&psum[0][myp][0];
        sv += *(const f4*)&psum[1][myp][0];
        sv += *(const f4*)&psum[2][myp][0];
        sv += *(const f4*)&psum[3][myp][0];
        const float dd0 = sigmoidf_(sv.x + bd2[0]);
        const float dd1 = sigmoidf_(sv.y + bd2[1]);
        const float dd2 = sigmoidf_(sv.z + bd2[2]);
        const float r1o = sigmoidf_(sv.w + bd2[6])*0.98f + 0.01f;
        float a2s = r1o*r1o; a2s = a2s*a2s;
        const float sclo = __expf(0.1f*__logf(fmaxf(a2s, 1e-6f)));

        // ---- geometry for (pt = myp, ray = c15), all in-lane ----
        float ct = sqrtf((1.0f-uv.x)/(1.0f+(a2s-1.0f)*uv.x));
        float st = sqrtf(fmaxf(1.0f-ct*ct,0.0f));
        float phi = 6.28318530717958647692f*uv.y;
        float hl0 = st*__cosf(phi), hl1 = st*__sinf(phi), hl2 = ct;
        float dvh = Vlx*hl0 + Vly*hl1 + Vlz*hl2;
        float t2 = dvh + dvh;
        float llx = fmaf(t2,hl0,-Vlx), lly = fmaf(t2,hl1,-Vly), llz = fmaf(t2,hl2,-Vlz);
        float linv = 1.0f/(sqrtf(llx*llx+lly*lly+llz*llz)+1e-8f);
        llx*=linv; lly*=linv; llz*=linv;
        float rv2w = bas[6]*llx + bas[7]*lly + bas[8]*llz;
        int w0 = pkh(bas[0]*llx + bas[1]*lly + bas[2]*llz,
                     bas[3]*llx + bas[4]*lly + bas[5]*llz);
        int w1 = pkh(rv2w, hl0);
        int w2 = pkh(hl1, hl2);
        int w3 = pkh(llx, lly);
        int w4 = pkh(llz, r1o);

        // B-fragments for the chunk's 4 points (packed shuffles)
        h8 af[4];
        #pragma unroll
        for (int pp = 0; pp < 4; pp++){
            const int srcl = pp*16 + c15;
            int u0 = __shfl(w0, srcl), u1 = __shfl(w1, srcl);
            int u2 = __shfl(w2, srcl), u3 = __shfl(w3, srcl);
            int u4 = __shfl(w4, srcl);
            const bool g0 = (kg == 0), g1 = (kg == 1);
            union { int i[4]; h8 h; } U;
            U.i[0] = g0 ? u0 : (g1 ? u4 : 0);
            U.i[1] = g0 ? u1 : 0;
            U.i[2] = g0 ? u2 : 0;
            U.i[3] = g0 ? u3 : 0;
            af[pp] = U.h;
        }

        // ---- transposed ray GEMM chained into layer-2 MFMA ----
        f4 S2[4];
        #pragma unroll
        for (int pp = 0; pp < 4; pp++) S2[pp] = f4{0.f,0.f,0.f,0.f};

        #pragma unroll 4
        for (int t = 0; t < 8; t++){
            const int j0 = 16*t + 4*kg;
            h8 Af = fragRT[t*64 + lane];
            h4 Wf = fragW2[t*64 + lane];
            #pragma unroll
            for (int pp = 0; pp < 4; pp++){
                f4 C = *(const f4*)&baseL[(4*ch+pp)*132 + j0];
                f4 d = mfma16(Af, af[pp], C);
                union { int i[2]; h4 h; } B2;
                B2.i[0] = relu2h(pkh(d.x, d.y));
                B2.i[1] = relu2h(pkh(d.z, d.w));
                S2[pp] = mfma16k16(Wf, B2.h, S2[pp]);
            }
        }

        // select this lane's point (pp = kg)
        f4 slo = (kg & 1) ? S2[1] : S2[0];
        f4 shi = (kg & 1) ? S2[3] : S2[2];
        f4 sS  = (kg & 2) ? shi : slo;

        // ---- epilogue: lane-local (pt=myp, ray=c15) ----
        float e0 = sigmoidf_(sS.x + bb2[0]);
        float e1 = sigmoidf_(sS.y + bb2[1]);
        float e2 = sigmoidf_(sS.z + bb2[2]);
        float lzp = fmaxf(rv2w, 0.f);
        f2 pA = { (lzp*1.0f+0.1f)*sclo*e0*mf0, (lzp*0.9f+0.1f)*sclo*e1*mf0 };
        f2 pB = { (lzp*0.8f+0.1f)*sclo*e2*mf0, mf0 };
        #pragma unroll
        for (int off = 1; off <= 8; off <<= 1){
            pA += shflxor2(pA, off);
            pB += shflxor2(pB, off);
        }
        if (c15 == 0){
            float den = pB.y + 1e-8f;
            out[myn*3+0] = pA.x/den + dd0;
            out[myn*3+1] = pA.y/den + dd1;
            out[myn*3+2] = pB.x/den + dd2;
        }

        __syncthreads();   // protect baseL/psum before next group's writes
    }
}

extern "C" void kernel_launch(void* const* d_in, const int* in_sizes, int n_in,
                              void* d_out, int out_size, void* d_ws, size_t ws_size,
                              hipStream_t stream) {
    const float* xyzs    = (const float*)d_in[0];
    const float* app     = (const float*)d_in[1];
    const float* vdirs   = (const float*)d_in[2];
    const float* normals = (const float*)d_in[3];
    const float* noise   = (const float*)d_in[4];
    const float* uu      = (const float*)d_in[5];
    const float* Wd1     = (const float*)d_in[6];
    const float* bd1     = (const float*)d_in[7];
    const float* Wd2     = (const float*)d_in[8];
    const float* bd2     = (const float*)d_in[9];
    const float* Wb1     = (const float*)d_in[10];
    const float* bb1     = (const float*)d_in[11];
    const float* Wb2     = (const float*)d_in[12];
    const float* bb2     = (const float*)d_in[13];
    const void*  raym    = d_in[15];
    float* wsf = (float*)d_ws;
    float* out = (float*)d_out;

    prep<<<16, 256, 0, stream>>>(Wd1, Wb1, Wb2, Wd2, (const unsigned int*)raym, wsf);
    rb_main<<<GRID, BLOCK, 0, stream>>>(xyzs, app, vdirs, normals, noise, uu,
                                        bd1, bd2, bb1, bb2,
                                        raym, wsf, out);
}

// Round 20
// 44.909 us; speedup vs baseline: 1.2579x; 1.2579x over previous
//
#include <hip/hip_runtime.h>
#include <hip/hip_bf16.h>
#include <math.h>

#define MRAY 16
#define BLOCK 256
#define GRID 4096   // 4096 blocks * 16 pts = 65536

typedef float f2 __attribute__((ext_vector_type(2)));
typedef float f4 __attribute__((ext_vector_type(4)));
typedef _Float16 h8 __attribute__((ext_vector_type(8)));
typedef _Float16 h4 __attribute__((ext_vector_type(4)));
typedef __fp16 fp16x2 __attribute__((ext_vector_type(2)));

__device__ __forceinline__ float sigmoidf_(float x){ return 1.0f/(1.0f+__expf(-x)); }
__device__ __forceinline__ f2 shflxor2(f2 v, int off){
    f2 r; r.x = __shfl_xor(v.x, off); r.y = __shfl_xor(v.y, off); return r;
}
__device__ __forceinline__ f4 mfma16(h8 a, h8 b, f4 c){
    return __builtin_amdgcn_mfma_f32_16x16x32_f16(a, b, c, 0, 0, 0);
}
__device__ __forceinline__ f4 mfma16k16(h4 a, h4 b, f4 c){
    return __builtin_amdgcn_mfma_f32_16x16x16f16(a, b, c, 0, 0, 0);
}
__device__ __forceinline__ int pkh(float a, float b){
    union { fp16x2 h; int i; } u;
    u.h = __builtin_amdgcn_cvt_pkrtz(a, b);
    return u.i;
}
// packed f16 relu on a 2xf16 word (relu∘cvt == cvt∘relu: cvt_pkrtz monotonic, ±0 safe)
__device__ __forceinline__ int relu2h(int w){
    union { int i; fp16x2 h; } u; u.i = w;
    fp16x2 z = {(__fp16)0.f, (__fp16)0.f};
    u.h = __builtin_elementwise_max(u.h, z);
    return u.i;
}

// ws float layout:
//   [0]      flag (int)
//   [16]     fragDT:  h8[1024]  (TRANSPOSED Wd1: A[row=j][k], k-order [app48,xyz3,vdir3,pad10], 2 Ksteps)
//   [4112]   fragB:   h8[1024]  (Wb1 const rows, k-order [nf48,eV3,eN3,pad10])
//   [8208]   fragRT:  h8[512]   (transposed ray weights: A[row=j][k], k<9 -> Wb1 ray rows, k==9 -> row63)
//   [10256]  fragW2:  h4[512]   (A-frag layer-2 ray: rows 4q+c = Wb2^T[c] (c<3), row 4q+3 = 0)
//   [11280]  fragWd2t:h4[512]   (A-frag layer-2 dense: rows 4q+c = Wd2^T[{0,1,2,6}[c]])
__global__ __launch_bounds__(256) void prep(
    const float* __restrict__ Wd1, const float* __restrict__ Wb1,
    const float* __restrict__ Wb2, const float* __restrict__ Wd2,
    const unsigned int* __restrict__ rm, float* __restrict__ ws)
{
    const int gt = blockIdx.x*256 + threadIdx.x;
    h8* fragDT  = (h8*)(ws + 16);
    h8* fragB   = fragDT + 1024;
    h8* fragRT  = fragB + 1024;
    h4* fragW2  = (h4*)(ws + 10256);
    h4* fragWd2t= (h4*)(ws + 11280);
    if (gt < 1024){
        // fragDT: A[row=j][k]; lane l: j=16t+(l&15), k=32ks+8gg+b
        int ks = gt >> 9, t = (gt >> 6) & 7, l = gt & 63;
        int j = 16*t + (l & 15), gg = (l >> 4) & 3;
        h8 v;
        #pragma unroll
        for (int b = 0; b < 8; b++){
            int k = 32*ks + 8*gg + b;
            int row = (k < 48) ? 6 + k : (k < 54 ? k - 48 : -1);
            v[b] = (_Float16)(row >= 0 ? Wd1[row*128 + j] : 0.0f);
        }
        fragDT[gt] = v;
    } else if (gt < 2048){
        int e = gt - 1024;
        int ks = e >> 9, t = (e >> 6) & 7, l = e & 63;
        int col = 16*t + (l & 15), gg = (l >> 4) & 3;
        h8 v;
        #pragma unroll
        for (int b = 0; b < 8; b++){
            int k = 32*ks + 8*gg + b;
            int row = (k < 48) ? 15 + k : (k < 51 ? k - 48 : (k < 54 ? k - 45 : -1));
            v[b] = (_Float16)(row >= 0 ? Wb1[row*128 + col] : 0.0f);
        }
        fragB[e] = v;
    } else if (gt < 2560){
        // fragRT: A[row=j][k]; lane l: j=16t+(l&15), k=8gg+b
        int e = gt - 2048;
        int t = e >> 6, l = e & 63;
        int j = 16*t + (l & 15), gg = (l >> 4) & 3;
        h8 v;
        #pragma unroll
        for (int b = 0; b < 8; b++){
            int k = 8*gg + b;
            int row = (k < 3) ? 3 + k : (k < 9 ? 6 + k : (k == 9 ? 63 : -1));
            v[b] = (_Float16)(row >= 0 ? Wb1[row*128 + j] : 0.0f);
        }
        fragRT[e] = v;
    } else if (gt < 3072){
        // fragW2: A[row=4q+c][k=j_local] = Wb2^T[c][16t+k] (c<3), rows 4q+3 zero
        int e = gt - 2560;
        int t = e >> 6, l = e & 63;
        int r = l & 15, kg = (l >> 4) & 3;
        int c = r & 3;
        h4 v;
        #pragma unroll
        for (int i = 0; i < 4; i++){
            int j = 16*t + 4*kg + i;
            v[i] = (_Float16)((c < 3) ? Wb2[j*3 + c] : 0.0f);
        }
        fragW2[e] = v;
    } else if (gt < 3584){
        // fragWd2t: A[row=4q+c][k=j_local] = Wd2[j][{0,1,2,6}[c]]
        int e = gt - 3072;
        int t = e >> 6, l = e & 63;
        int r = l & 15, kg = (l >> 4) & 3;
        int c = r & 3;
        int col = (c == 3) ? 6 : c;
        h4 v;
        #pragma unroll
        for (int i = 0; i < 4; i++){
            int j = 16*t + 4*kg + i;
            v[i] = (_Float16)Wd2[j*9 + col];
        }
        fragWd2t[e] = v;
    } else if (gt >= 3584 && gt < 3648){
        // one full wave: classify ray_mask dtype
        int l = gt - 3584;
        bool bad=false, isf32=false, odd_nz=false, even_one=false;
        #pragma unroll
        for (int i = 0; i < 8; i++){
            int idx = l*8 + i;
            unsigned v = rm[idx];
            if (v != 0u && v != 1u && v != 0x3F800000u) bad = true;
            if (v == 0x3F800000u) isf32 = true;
            if ((idx & 1) && v != 0u) odd_nz = true;
            if (!(idx & 1) && v != 0u) even_one = true;
        }
        unsigned long long Bb = __ballot(bad);
        unsigned long long Bf = __ballot(isf32);
        unsigned long long Bo = __ballot(odd_nz);
        unsigned long long Be = __ballot(even_one);
        if (l == 0){
            int f;
            if (Bb) f = 0;            // uint8 bool
            else if (Bf) f = 1;       // f32 / i32 words
            else if (!Bo && Be) f = 2; // int64
            else f = 1;
            ((int*)ws)[0] = f;
        }
    }
}

// 4 waves per block, 16 points per block. Cooperative pre-phase (wave w: N-tiles
// {2w,2w+1}) with BOTH GEMMs' layer-2 fused via chained MFMA; one barrier; then
// each wave does chunk ch=wid with the transposed ray GEMM chain. All reductions
// via matrix core; no shuffle-reduce anywhere in the pre-phase.
__global__ __launch_bounds__(BLOCK, 2) void rb_main(
    const float* __restrict__ xyzs, const float* __restrict__ app,
    const float* __restrict__ vdirs, const float* __restrict__ normals,
    const float* __restrict__ noise, const float* __restrict__ uu,
    const float* __restrict__ bd1, const float* __restrict__ bd2,
    const float* __restrict__ bb1, const float* __restrict__ bb2,
    const void* __restrict__ raym, const float* __restrict__ wsf,
    float* __restrict__ out)
{
    __shared__ float baseL[16*132];    // 8448 B: base row-major [pt][128] (stride 132)
    __shared__ float psum[4][16][4];   // 1 KB: per-wave dense layer-2 partials [wave][pt][out]

    const int tid  = threadIdx.x;
    const int lane = tid & 63;
    const int ch   = __builtin_amdgcn_readfirstlane(tid >> 6);  // wave id == chunk id
    const int pbase = blockIdx.x * 16;

    const int flag = ((const int*)wsf)[0];
    const h8* fragDT  = (const h8*)(wsf + 16);
    const h8* fragB   = fragDT + 1024;
    const h8* fragRT  = fragB + 1024;
    const h4* fragW2  = (const h4*)(wsf + 10256);
    const h4* fragWd2t= (const h4*)(wsf + 11280);

    const int c15 = lane & 15;
    const int kg  = lane >> 4;
    const int myn = pbase + 4*ch + kg;     // this lane's geometry point

    // ---- prefetch: uu pair + ray-mask decode (lane-local: pt=4ch+kg, ray=c15) ----
    f2 uv = *(const f2*)&uu[(myn*MRAY + c15)*2];
    float mf0;
    {
        int midx = myn*MRAY + c15;
        bool mk;
        if (flag == 0)      mk = ((const unsigned char*)raym)[midx] != 0;
        else if (flag == 2) mk = ((const unsigned long long*)raym)[midx] != 0ull;
        else                mk = ((const unsigned int*)raym)[midx] != 0u;
        mf0 = mk ? 1.f : 0.f;
    }

    // ---- phase 1: basis + local V for pt = lane (lanes 0..15; redundant per wave) ----
    float bs[12];
    #pragma unroll
    for (int i = 0; i < 12; i++) bs[i] = 0.f;
    if (lane < 16){
        int n = pbase + lane;
        float nx = normals[n*3+0], ny = normals[n*3+1], nz = normals[n*3+2];
        float inv = 1.0f/(sqrtf(nx*nx+ny*ny+nz*nz)+1e-8f);
        float bx = nx*inv, by = ny*inv, bz = nz*inv;
        float ux, uy, uz;
        if (fabsf(bz) < 0.99f){ ux=0.f; uy=0.f; uz=1.f; } else { ux=1.f; uy=0.f; uz=0.f; }
        float tx = uy*bz-uz*by, ty = uz*bx-ux*bz, tz = ux*by-uy*bx;
        float tin = 1.0f/(sqrtf(tx*tx+ty*ty+tz*tz)+1e-8f);
        tx*=tin; ty*=tin; tz*=tin;
        float ex = by*tz-bz*ty, ey = bz*tx-bx*tz, ez = bx*ty-by*tx;
        bs[0]=tx; bs[1]=ex; bs[2]=bx; bs[3]=ty; bs[4]=ey; bs[5]=by; bs[6]=tz; bs[7]=ez; bs[8]=bz;
        float vx = vdirs[n*3+0], vy = vdirs[n*3+1], vz = vdirs[n*3+2];
        bs[9]  = -(tx*vx + ty*vy + tz*vz);
        bs[10] = -(ex*vx + ey*vy + ez*vz);
        bs[11] = -(bx*vx + by*vy + bz*vz);
    }

    // ---- input fragments for GEMM1/2 (lane: pt = c15, k-slice = kg; packed cvts) ----
    const int n_p = pbase + c15;
    float xv0=0.f,xv1=0.f,xv2=0.f,vv0=0.f,vv1=0.f,vv2=0.f;
    if (kg == 2){
        xv0 = xyzs[n_p*3+0]; xv1 = xyzs[n_p*3+1]; xv2 = xyzs[n_p*3+2];
        vv0 = vdirs[n_p*3+0]; vv1 = vdirs[n_p*3+1]; vv2 = vdirs[n_p*3+2];
    }
    float bn0 = __shfl(bs[2], c15), bn1 = __shfl(bs[5], c15), bn2 = __shfl(bs[8], c15);
    const float* ap = app + n_p*48;
    const float* nz = noise + n_p*48;
    h8 afD[2], afB[2];
    #pragma unroll
    for (int ks = 0; ks < 2; ks++){
        const int k0 = 32*ks + 8*kg;
        union { int i[4]; h8 h; } UD, UB;
        if (k0 <= 40){
            f4 a0 = *(const f4*)(ap + k0);
            f4 a1 = *(const f4*)(ap + k0 + 4);
            f4 z0 = *(const f4*)(nz + k0);
            f4 z1 = *(const f4*)(nz + k0 + 4);
            UD.i[0] = pkh(a0.x, a0.y); UD.i[1] = pkh(a0.z, a0.w);
            UD.i[2] = pkh(a1.x, a1.y); UD.i[3] = pkh(a1.z, a1.w);
            UB.i[0] = pkh(fmaf(0.01f,z0.x,a0.x), fmaf(0.01f,z0.y,a0.y));
            UB.i[1] = pkh(fmaf(0.01f,z0.z,a0.z), fmaf(0.01f,z0.w,a0.w));
            UB.i[2] = pkh(fmaf(0.01f,z1.x,a1.x), fmaf(0.01f,z1.y,a1.y));
            UB.i[3] = pkh(fmaf(0.01f,z1.z,a1.z), fmaf(0.01f,z1.w,a1.w));
        } else if (k0 == 48){
            UD.i[0] = pkh(xv0, xv1); UD.i[1] = pkh(xv2, vv0);
            UD.i[2] = pkh(vv1, vv2); UD.i[3] = 0;
            UB.i[0] = pkh(-vv0, -vv1); UB.i[1] = pkh(-vv2, bn0);
            UB.i[2] = pkh(bn1, bn2);   UB.i[3] = 0;
        } else {
            UD.i[0]=0; UD.i[1]=0; UD.i[2]=0; UD.i[3]=0;
            UB.i[0]=0; UB.i[1]=0; UB.i[2]=0; UB.i[3]=0;
        }
        afD[ks]=UD.h; afB[ks]=UB.h;
    }

    // ---- GEMM1 transposed (dense layer1) chained into layer-2 MFMA, 2 N-tiles ----
    f4 S1 = {0.f,0.f,0.f,0.f};
    #pragma unroll
    for (int tt = 0; tt < 2; tt++){
        const int t = 2*ch + tt;
        const int j0 = 16*t + 4*kg;
        f4 C = *(const f4*)&bd1[j0];
        f4 d = mfma16(fragDT[t*64 + lane], afD[0], C);
        d = mfma16(fragDT[512 + t*64 + lane], afD[1], d);
        union { int i[2]; h4 h; } B2;
        B2.i[0] = relu2h(pkh(d.x, d.y));
        B2.i[1] = relu2h(pkh(d.z, d.w));
        S1 = mfma16k16(fragWd2t[t*64 + lane], B2.h, S1);
    }
    if (kg == 0)
        *(f4*)&psum[ch][c15][0] = S1;

    // ---- GEMM2 (bounce const part), this wave's 2 N-tiles -> baseL [pt][j] ----
    #pragma unroll
    for (int tt = 0; tt < 2; tt++){
        const int t = 2*ch + tt;
        const int col = 16*t + c15;
        float bias = bb1[col];
        f4 D = {bias,bias,bias,bias};
        D = mfma16(afB[0], fragB[t*64 + lane], D);
        D = mfma16(afB[1], fragB[512 + t*64 + lane], D);
        baseL[(4*kg+0)*132 + col] = D.x;
        baseL[(4*kg+1)*132 + col] = D.y;
        baseL[(4*kg+2)*132 + col] = D.z;
        baseL[(4*kg+3)*132 + col] = D.w;
    }

    __syncthreads();   // psum + baseL complete

    // ---- per-lane scalars for pt = c15 (sum 4 wave-partials) ----
    f4 sv = *(const f4*)&psum[0][c15][0];
    sv += *(const f4*)&psum[1][c15][0];
    sv += *(const f4*)&psum[2][c15][0];
    sv += *(const f4*)&psum[3][c15][0];
    float dv0 = sigmoidf_(sv.x + bd2[0]);
    float dv1 = sigmoidf_(sv.y + bd2[1]);
    float dv2 = sigmoidf_(sv.z + bd2[2]);
    float r1v = sigmoidf_(sv.w + bd2[6])*0.98f + 0.01f;
    float a2v = r1v*r1v; a2v = a2v*a2v;
    float sclv = __expf(0.1f*__logf(fmaxf(a2v, 1e-6f)));

    // own-point scalars (pt = 4ch+kg)
    const float r1o  = __shfl(r1v,  4*ch + kg);
    const float sclo = __shfl(sclv, 4*ch + kg);
    const float a2s  = __shfl(a2v,  4*ch + kg);

    // ---- geometry for (pt = 4ch+kg, ray = c15) ----
    const int pt = 4*ch + kg;
    float bas[9];
    #pragma unroll
    for (int i = 0; i < 9; i++) bas[i] = __shfl(bs[i], pt);
    float Vlx = __shfl(bs[9],  pt);
    float Vly = __shfl(bs[10], pt);
    float Vlz = __shfl(bs[11], pt);

    float ct = sqrtf((1.0f-uv.x)/(1.0f+(a2s-1.0f)*uv.x));
    float st = sqrtf(fmaxf(1.0f-ct*ct,0.0f));
    float phi = 6.28318530717958647692f*uv.y;
    float hl0 = st*__cosf(phi), hl1 = st*__sinf(phi), hl2 = ct;
    float dvh = Vlx*hl0 + Vly*hl1 + Vlz*hl2;
    float t2 = dvh + dvh;
    float llx = fmaf(t2,hl0,-Vlx), lly = fmaf(t2,hl1,-Vly), llz = fmaf(t2,hl2,-Vlz);
    float linv = 1.0f/(sqrtf(llx*llx+lly*lly+llz*llz)+1e-8f);
    llx*=linv; lly*=linv; llz*=linv;
    float rv2w = bas[6]*llx + bas[7]*lly + bas[8]*llz;   // world L.z (for incoming)
    // packed f16 rv: (L0,L1),(L2,h0),(h1,h2),(d0,d1),(d2,r1) -- k=9 carries r1 (pairs with Wb1 row63)
    int w0 = pkh(bas[0]*llx + bas[1]*lly + bas[2]*llz,
                 bas[3]*llx + bas[4]*lly + bas[5]*llz);
    int w1 = pkh(rv2w, hl0);
    int w2 = pkh(hl1, hl2);
    int w3 = pkh(llx, lly);
    int w4 = pkh(llz, r1o);

    // B-fragments for the chunk's 4 points (packed shuffles; af layout == B layout)
    h8 af[4];
    #pragma unroll
    for (int pp = 0; pp < 4; pp++){
        const int srcl = pp*16 + c15;
        int u0 = __shfl(w0, srcl), u1 = __shfl(w1, srcl);
        int u2 = __shfl(w2, srcl), u3 = __shfl(w3, srcl);
        int u4 = __shfl(w4, srcl);
        const bool g0 = (kg == 0), g1 = (kg == 1);
        union { int i[4]; h8 h; } U;
        U.i[0] = g0 ? u0 : (g1 ? u4 : 0);
        U.i[1] = g0 ? u1 : 0;
        U.i[2] = g0 ? u2 : 0;
        U.i[3] = g0 ? u3 : 0;
        af[pp] = U.h;
    }

    // ---- transposed ray GEMM chained into layer-2 MFMA ----
    f4 S2[4];
    #pragma unroll
    for (int pp = 0; pp < 4; pp++) S2[pp] = f4{0.f,0.f,0.f,0.f};

    #pragma unroll 4
    for (int t = 0; t < 8; t++){
        const int j0 = 16*t + 4*kg;
        h8 Af = fragRT[t*64 + lane];
        h4 Wf = fragW2[t*64 + lane];
        #pragma unroll
        for (int pp = 0; pp < 4; pp++){
            f4 C = *(const f4*)&baseL[(4*ch+pp)*132 + j0];
            f4 d = mfma16(Af, af[pp], C);
            union { int i[2]; h4 h; } B2;
            B2.i[0] = relu2h(pkh(d.x, d.y));
            B2.i[1] = relu2h(pkh(d.z, d.w));
            S2[pp] = mfma16k16(Wf, B2.h, S2[pp]);
        }
    }

    // select this lane's point (pp = kg) -- S[c] = S2[kg][c]
    f4 slo = (kg & 1) ? S2[1] : S2[0];
    f4 shi = (kg & 1) ? S2[3] : S2[2];
    f4 sS  = (kg & 2) ? shi : slo;

    // ---- epilogue: everything lane-local (pt=4ch+kg, ray=c15) ----
    float dd0 = __shfl(dv0, 4*ch + kg);
    float dd1 = __shfl(dv1, 4*ch + kg);
    float dd2 = __shfl(dv2, 4*ch + kg);
    float e0 = sigmoidf_(sS.x + bb2[0]);
    float e1 = sigmoidf_(sS.y + bb2[1]);
    float e2 = sigmoidf_(sS.z + bb2[2]);
    float lzp = fmaxf(rv2w, 0.f);
    f2 pA = { (lzp*1.0f+0.1f)*sclo*e0*mf0, (lzp*0.9f+0.1f)*sclo*e1*mf0 };
    f2 pB = { (lzp*0.8f+0.1f)*sclo*e2*mf0, mf0 };
    #pragma unroll
    for (int off = 1; off <= 8; off <<= 1){
        pA += shflxor2(pA, off);
        pB += shflxor2(pB, off);
    }
    if (c15 == 0){
        float den = pB.y + 1e-8f;
        out[myn*3+0] = pA.x/den + dd0;
        out[myn*3+1] = pA.y/den + dd1;
        out[myn*3+2] = pB.x/den + dd2;
    }
}

extern "C" void kernel_launch(void* const* d_in, const int* in_sizes, int n_in,
                              void* d_out, int out_size, void* d_ws, size_t ws_size,
                              hipStream_t stream) {
    const float* xyzs    = (const float*)d_in[0];
    const float* app     = (const float*)d_in[1];
    const float* vdirs   = (const float*)d_in[2];
    const float* normals = (const float*)d_in[3];
    const float* noise   = (const float*)d_in[4];
    const float* uu      = (const float*)d_in[5];
    const float* Wd1     = (const float*)d_in[6];
    const float* bd1     = (const float*)d_in[7];
    const float* Wd2     = (const float*)d_in[8];
    const float* bd2     = (const float*)d_in[9];
    const float* Wb1     = (const float*)d_in[10];
    const float* bb1     = (const float*)d_in[11];
    const float* Wb2     = (const float*)d_in[12];
    const float* bb2     = (const float*)d_in[13];
    const void*  raym    = d_in[15];
    float* wsf = (float*)d_ws;
    float* out = (float*)d_out;

    prep<<<16, 256, 0, stream>>>(Wd1, Wb1, Wb2, Wd2, (const unsigned int*)raym, wsf);
    rb_main<<<GRID, BLOCK, 0, stream>>>(xyzs, app, vdirs, normals, noise, uu,
                                        bd1, bd2, bb1, bb2,
                                        raym, wsf, out);
}